// Round 5
// baseline (659.376 us; speedup 1.0000x reference)
//
#include <hip/hip_runtime.h>
#include <hip/hip_fp16.h>

// GIN (5 layers) + BN + pool + MLP head, fused pipeline for MI355X. Round 7.
// R6: atomic-free stats -> layers ~50us; count_fill now top kernel (52us,
// WRITE_SIZE 48MB from write-allocate of scattered 4B stores into 12.8MB ELL).
// R7: (a) ushort ELL (N=50000 < 65536): halves ELL bytes, dirty lines, and
// index stream. (b) degree-sorted node permutation (counting sort, 3 tiny
// kernels): waves process equal-degree nodes -> j-loop runs ~mean degree
// instead of max-of-8 (~25 vs 16) -> kills ~35% of gather iterations.
// (c) gather consumes 8 neighbors per 16B ushort8 index load (pad to 8).

constexpr int N = 50000;
constexpr int E = 800000;
constexpr int G = 128;
constexpr int MAXDEG = 64;
constexpr float BN_EPS = 1e-5f;

__device__ inline float4 ld4(const float* p) { return *(const float4*)p; }
__device__ inline void st4(float* p, float4 v) { *(float4*)p = v; }

// accumulate 8 halves (raw float4 bits) into float a[8]
__device__ inline void acc8(float* a, float4 raw) {
    const __half2* h2 = (const __half2*)&raw;
#pragma unroll
    for (int i = 0; i < 4; i++) {
        float2 f2 = __half22float2(h2[i]);
        a[2 * i] += f2.x; a[2 * i + 1] += f2.y;
    }
}

union HF2 { __half2 h2[2]; float2 f2; };

__global__ __launch_bounds__(256) void count_fill_kernel(
    const int* __restrict__ ei, int* __restrict__ deg, unsigned short* __restrict__ ell)
{
    int e = blockIdx.x * 256 + threadIdx.x;
    if (e < E) {
        int s = ei[e];
        int d = ei[E + e];
        int slot = atomicAdd(&deg[d], 1);
        if (slot < MAXDEG) ell[d * MAXDEG + slot] = (unsigned short)s;
    }
}

// pad each ELL row to a multiple of 8 slots with the zero-row index N
__global__ __launch_bounds__(256) void pad_kernel(
    const int* __restrict__ deg, unsigned short* __restrict__ ell)
{
    int n = blockIdx.x * 256 + threadIdx.x;
    if (n < N) {
        int dgc = min(deg[n], MAXDEG);
        int p = (dgc + 7) & ~7;
        for (int s = dgc; s < p; s++) ell[n * MAXDEG + s] = (unsigned short)N;
    }
}

// ---- degree counting sort: hist -> exclusive scan -> scatter ----
__global__ __launch_bounds__(256) void hist_kernel(
    const int* __restrict__ deg, int* __restrict__ hist)
{
    int n = blockIdx.x * 256 + threadIdx.x;
    if (n < N) atomicAdd(&hist[min(deg[n], MAXDEG)], 1);
}

__global__ void scan_kernel(int* __restrict__ hist)
{
    // single thread, 65 bins: exclusive prefix sum
    int run = 0;
    for (int b = 0; b <= MAXDEG; b++) { int h = hist[b]; hist[b] = run; run += h; }
}

__global__ __launch_bounds__(256) void scatter_perm_kernel(
    const int* __restrict__ deg, int* __restrict__ hist, int* __restrict__ perm)
{
    int n = blockIdx.x * 256 + threadIdx.x;
    if (n < N) {
        int slot = atomicAdd(&hist[min(deg[n], MAXDEG)], 1);
        perm[slot] = n;
    }
}

// out[n][64] = x[n][128] @ W[128][64], stored fp16; 64 rows per block
__global__ __launch_bounds__(256) void xw_kernel(
    const float* __restrict__ x, const float* __restrict__ W, __half* __restrict__ out)
{
    int tid = threadIdx.x;
    int ty = tid >> 4, tx = tid & 15;
    int base = blockIdx.x * 64;

    float acc[4][4];
#pragma unroll
    for (int r = 0; r < 4; r++)
#pragma unroll
        for (int cc = 0; cc < 4; cc++) acc[r][cc] = 0.f;

    int rr[4];
#pragma unroll
    for (int r = 0; r < 4; r++) rr[r] = min(base + 4 * ty + r, N - 1);

#pragma unroll 4
    for (int c = 0; c < 128; c++) {
        float4 w4 = ld4(W + c * 64 + 4 * tx);
#pragma unroll
        for (int r = 0; r < 4; r++) {
            float a = x[(size_t)rr[r] * 128 + c];
            acc[r][0] += a * w4.x; acc[r][1] += a * w4.y;
            acc[r][2] += a * w4.z; acc[r][3] += a * w4.w;
        }
    }
#pragma unroll
    for (int r = 0; r < 4; r++) {
        int node = base + 4 * ty + r;
        if (node < N) {
            HF2 u;
            u.h2[0] = __floats2half2_rn(acc[r][0], acc[r][1]);
            u.h2[1] = __floats2half2_rn(acc[r][2], acc[r][3]);
            *(float2*)(out + (size_t)node * 64 + 4 * tx) = u.f2;
        }
    }
}

// sum nb per-block partials (each 128 floats) into stats[128].
__global__ __launch_bounds__(64) void reduce_stats_kernel(
    const float* __restrict__ partials, float* __restrict__ stats, int nb)
{
    int c = blockIdx.x;
    int lane = threadIdx.x;
    float s = 0.f;
    for (int i = lane; i < nb; i += 64)
        s += partials[(size_t)i * 128 + c];
#pragma unroll
    for (int off = 32; off > 0; off >>= 1)
        s += __shfl_down(s, off, 64);
    if (lane == 0) stats[c] = s;
}

// Fused GIN layer. hin fp16, N+1 rows (row N = zeros). 64 slots per block,
// slot -> node via degree-sorted perm. ELL ushort, rows padded to 8.
template <bool FIRST>
__global__ __launch_bounds__(256) void layer_kernel(
    const __half* __restrict__ hin, const unsigned short* __restrict__ ell,
    const int* __restrict__ deg, const int* __restrict__ perm,
    const float* __restrict__ statsPrev, const float* __restrict__ gamma, const float* __restrict__ beta,
    const float* __restrict__ bias0,
    const float* __restrict__ W1, const float* __restrict__ b1,
    const float* __restrict__ W2, const float* __restrict__ b2,
    __half* __restrict__ hout, float* __restrict__ statsPart)
{
    __shared__ float sV[64 * 68];   // stride 68
    __shared__ float sStat[128];

    int tid = threadIdx.x, lane = tid & 63, wv = tid >> 6;
    if (tid < 128) sStat[tid] = 0.f;

    int base = blockIdx.x * 64;
    int n8 = lane >> 3, f = lane & 7;   // node-sub (8), feature-oct (8)

    // per-lane channel oct f*8..f*8+7 epilogue params
    float sc[8], sh[8], b0[8];
    if constexpr (FIRST) {
#pragma unroll
        for (int q = 0; q < 2; q++) {
            float4 b4 = ld4(bias0 + 8 * f + 4 * q);
            b0[4 * q + 0] = b4.x; b0[4 * q + 1] = b4.y;
            b0[4 * q + 2] = b4.z; b0[4 * q + 3] = b4.w;
        }
    } else {
#pragma unroll
        for (int q = 0; q < 2; q++) {
            float4 s1 = ld4(statsPrev + 8 * f + 4 * q);
            float4 s2 = ld4(statsPrev + 64 + 8 * f + 4 * q);
            float4 g4 = ld4(gamma + 8 * f + 4 * q);
            float4 be4 = ld4(beta + 8 * f + 4 * q);
            float m[4] = { s1.x / N, s1.y / N, s1.z / N, s1.w / N };
            float v2[4] = { s2.x / N, s2.y / N, s2.z / N, s2.w / N };
            float gg[4] = { g4.x, g4.y, g4.z, g4.w };
            float bb4[4] = { be4.x, be4.y, be4.z, be4.w };
#pragma unroll
            for (int i = 0; i < 4; i++) {
                float s = gg[i] * rsqrtf(v2[i] - m[i] * m[i] + BN_EPS);
                sc[4 * q + i] = s;
                sh[4 * q + i] = bb4[i] - m[i] * s;
            }
        }
    }

    // ---- phase A: gather; wave handles 8 slots at a time, 2 rounds ----
#pragma unroll
    for (int kk = 0; kk < 2; kk++) {
        int slot = base + wv * 16 + kk * 8 + n8;
        int nd = (slot < N) ? perm[slot] : N;
        int dg = (slot < N) ? deg[nd] : 0;
        int dgc = min(dg, MAXDEG);
        int p = (dgc + 7) & ~7;
        const unsigned short* row = ell + (size_t)nd * MAXDEG;

        float a0[8], a1[8], a2[8], a3[8];
#pragma unroll
        for (int i = 0; i < 8; i++) { a0[i] = 0.f; a1[i] = 0.f; a2[i] = 0.f; a3[i] = 0.f; }

        float4 rown = ld4((const float*)(hin + (size_t)nd * 64 + 8 * f));
        for (int j = 0; j < p; j += 8) {
            uint4 iv = *(const uint4*)(row + j);
            int i0 = iv.x & 0xFFFF, i1 = (int)(iv.x >> 16);
            int i2 = iv.y & 0xFFFF, i3 = (int)(iv.y >> 16);
            int i4 = iv.z & 0xFFFF, i5 = (int)(iv.z >> 16);
            int i6 = iv.w & 0xFFFF, i7 = (int)(iv.w >> 16);
            float4 r0 = ld4((const float*)(hin + (size_t)i0 * 64 + 8 * f));
            float4 r1 = ld4((const float*)(hin + (size_t)i1 * 64 + 8 * f));
            float4 r2 = ld4((const float*)(hin + (size_t)i2 * 64 + 8 * f));
            float4 r3 = ld4((const float*)(hin + (size_t)i3 * 64 + 8 * f));
            float4 r4 = ld4((const float*)(hin + (size_t)i4 * 64 + 8 * f));
            float4 r5 = ld4((const float*)(hin + (size_t)i5 * 64 + 8 * f));
            float4 r6 = ld4((const float*)(hin + (size_t)i6 * 64 + 8 * f));
            float4 r7 = ld4((const float*)(hin + (size_t)i7 * 64 + 8 * f));
            acc8(a0, r0); acc8(a1, r1); acc8(a2, r2); acc8(a3, r3);
            acc8(a0, r4); acc8(a1, r5); acc8(a2, r6); acc8(a3, r7);
        }
        acc8(a0, rown);

        float v[8];
#pragma unroll
        for (int i = 0; i < 8; i++) {
            float s = (a0[i] + a1[i]) + (a2[i] + a3[i]);
            if constexpr (FIRST) {
                v[i] = fmaxf(s + b0[i], 0.f);
            } else {
                v[i] = sc[i] * s + (float)(1 + dg) * sh[i];
            }
        }
        int ridx = wv * 16 + kk * 8 + n8;
        st4(sV + ridx * 68 + 8 * f,     make_float4(v[0], v[1], v[2], v[3]));
        st4(sV + ridx * 68 + 8 * f + 4, make_float4(v[4], v[5], v[6], v[7]));
    }
    __syncthreads();

    int ty = tid >> 4, tx = tid & 15;

    if constexpr (!FIRST) {
        // ---- phase B: H = relu(V @ W1 + b1), in-place into sV ----
        float acc[4][4];
#pragma unroll
        for (int cc = 0; cc < 4; cc++) {
            float b = b1[4 * tx + cc];
            acc[0][cc] = b; acc[1][cc] = b; acc[2][cc] = b; acc[3][cc] = b;
        }
#pragma unroll 4
        for (int c = 0; c < 64; c++) {
            float4 w4 = ld4(W1 + c * 64 + 4 * tx);
#pragma unroll
            for (int r = 0; r < 4; r++) {
                float a = sV[(4 * ty + r) * 68 + c];
                acc[r][0] += a * w4.x; acc[r][1] += a * w4.y;
                acc[r][2] += a * w4.z; acc[r][3] += a * w4.w;
            }
        }
        __syncthreads();
#pragma unroll
        for (int r = 0; r < 4; r++)
            st4(sV + (4 * ty + r) * 68 + 4 * tx,
                make_float4(fmaxf(acc[r][0], 0.f), fmaxf(acc[r][1], 0.f),
                            fmaxf(acc[r][2], 0.f), fmaxf(acc[r][3], 0.f)));
        __syncthreads();
    }

    // ---- phase C: O = relu(V @ W2 + b2), store fp16 (perm-scattered), stats ----
    float acc[4][4];
#pragma unroll
    for (int cc = 0; cc < 4; cc++) {
        float b = b2[4 * tx + cc];
        acc[0][cc] = b; acc[1][cc] = b; acc[2][cc] = b; acc[3][cc] = b;
    }
#pragma unroll 4
    for (int c = 0; c < 64; c++) {
        float4 w4 = ld4(W2 + c * 64 + 4 * tx);
#pragma unroll
        for (int r = 0; r < 4; r++) {
            float a = sV[(4 * ty + r) * 68 + c];
            acc[r][0] += a * w4.x; acc[r][1] += a * w4.y;
            acc[r][2] += a * w4.z; acc[r][3] += a * w4.w;
        }
    }
#pragma unroll
    for (int r = 0; r < 4; r++) {
        int slot = base + 4 * ty + r;
        if (slot < N) {
            int node = perm[slot];
            acc[r][0] = fmaxf(acc[r][0], 0.f); acc[r][1] = fmaxf(acc[r][1], 0.f);
            acc[r][2] = fmaxf(acc[r][2], 0.f); acc[r][3] = fmaxf(acc[r][3], 0.f);
            HF2 u;
            u.h2[0] = __floats2half2_rn(acc[r][0], acc[r][1]);
            u.h2[1] = __floats2half2_rn(acc[r][2], acc[r][3]);
            *(float2*)(hout + (size_t)node * 64 + 4 * tx) = u.f2;
        } else {
            acc[r][0] = acc[r][1] = acc[r][2] = acc[r][3] = 0.f;
        }
    }
#pragma unroll
    for (int cc = 0; cc < 4; cc++) {
        float s = 0.f, q = 0.f;
#pragma unroll
        for (int r = 0; r < 4; r++) { s += acc[r][cc]; q += acc[r][cc] * acc[r][cc]; }
        atomicAdd(&sStat[4 * tx + cc], s);
        atomicAdd(&sStat[64 + 4 * tx + cc], q);
    }
    __syncthreads();
    if (tid < 128) statsPart[(size_t)blockIdx.x * 128 + tid] = sStat[tid];
}

// pooled[g] = scale*sum_{n in g} h[n] + cnt*shift; z=relu(p@fc1+b1); z@fc2+b2; log_softmax
__global__ __launch_bounds__(256) void pool_head_kernel(
    const __half* __restrict__ h, const int* __restrict__ batch,
    const float* __restrict__ stats, const float* __restrict__ gamma, const float* __restrict__ beta,
    const float* __restrict__ fc1w, const float* __restrict__ fc1b,
    const float* __restrict__ fc2w, const float* __restrict__ fc2b,
    float* __restrict__ out)
{
    __shared__ float sacc[4][64];
    __shared__ float sp[64];
    __shared__ float sz[64];
    __shared__ float so[10];

    int g = blockIdx.x;
    int lane = threadIdx.x & 63, wv = threadIdx.x >> 6;

    int start, end;
    {
        int lo = 0, hi = N;
        while (lo < hi) { int mid = (lo + hi) >> 1; if (batch[mid] < g) lo = mid + 1; else hi = mid; }
        start = lo;
        lo = start; hi = N;
        while (lo < hi) { int mid = (lo + hi) >> 1; if (batch[mid] < g + 1) lo = mid + 1; else hi = mid; }
        end = lo;
    }

    float acc = 0.f;
    for (int node = start + wv; node < end; node += 4)
        acc += __half2float(h[(size_t)node * 64 + lane]);
    sacc[wv][lane] = acc;
    __syncthreads();

    if (wv == 0) {
        float mean = stats[lane] * (1.f / N);
        float var  = stats[64 + lane] * (1.f / N) - mean * mean;
        float sc = gamma[lane] * rsqrtf(var + BN_EPS);
        float sh = beta[lane] - mean * sc;
        float t = sacc[0][lane] + sacc[1][lane] + sacc[2][lane] + sacc[3][lane];
        sp[lane] = sc * t + (float)(end - start) * sh;
    }
    __syncthreads();
    if (wv == 0) {
        float a = fc1b[lane];
#pragma unroll
        for (int c = 0; c < 64; c++) a += sp[c] * fc1w[c * 64 + lane];
        sz[lane] = fmaxf(a, 0.f);
    }
    __syncthreads();
    if (wv == 0 && lane < 10) {
        float z = fc2b[lane];
#pragma unroll
        for (int j = 0; j < 64; j++) z += sz[j] * fc2w[j * 10 + lane];
        so[lane] = z;
    }
    __syncthreads();
    if (wv == 0 && lane < 10) {
        float m = -1e30f;
#pragma unroll
        for (int c = 0; c < 10; c++) m = fmaxf(m, so[c]);
        float s = 0.f;
#pragma unroll
        for (int c = 0; c < 10; c++) s += expf(so[c] - m);
        out[g * 10 + lane] = so[lane] - m - logf(s);
    }
}

extern "C" void kernel_launch(void* const* d_in, const int* in_sizes, int n_in,
                              void* d_out, int out_size, void* d_ws, size_t ws_size,
                              hipStream_t stream)
{
    const float* x    = (const float*)d_in[0];
    const int*   ei   = (const int*)  d_in[1];
    const int*   batch= (const int*)  d_in[2];
    const float* W1a  = (const float*)d_in[3];
    const float* b1a  = (const float*)d_in[4];
    const float* W1b  = (const float*)d_in[5];
    const float* b1b  = (const float*)d_in[6];
    const float* Wa   = (const float*)d_in[7];
    const float* ba   = (const float*)d_in[8];
    const float* Wb   = (const float*)d_in[9];
    const float* bb   = (const float*)d_in[10];
    const float* gammas = (const float*)d_in[11];
    const float* betas  = (const float*)d_in[12];
    const float* fc1w = (const float*)d_in[13];
    const float* fc1b = (const float*)d_in[14];
    const float* fc2w = (const float*)d_in[15];
    const float* fc2b = (const float*)d_in[16];
    float* out = (float*)d_out;

    // workspace carve (bufA/bufB 128B-aligned so each 64-half row = 1 line)
    char* w = (char*)d_ws;
    int*            deg      = (int*)w;                      // @0       200,000 B (zeroed)
    int*            hist     = (int*)(w + 200000);           // @200,000 260 B (zeroed)
    float*          stats    = (float*)(w + 200704);         // @200,704 2,560 B
    unsigned short* ell      = (unsigned short*)(w + 203264);// @203,264 6,400,000 B
    int*            perm     = (int*)(w + 6603264);          // @6,603,264 200,000 B
    __half*         bufA     = (__half*)(w + 6803328);       // @6,803,328 6,400,128 B
    __half*         bufB     = (__half*)(w + 13203456);      // @13,203,456 6,400,128 B
    float*          partials = (float*)(w + 19603584);       // @19,603,584 400,384 B

    hipMemsetAsync(d_ws, 0, 200260, stream);                 // deg + hist
    hipMemsetAsync(bufA + (size_t)N * 64, 0, 128, stream);   // zero row N
    hipMemsetAsync(bufB + (size_t)N * 64, 0, 128, stream);

    count_fill_kernel<<<(E + 255) / 256, 256, 0, stream>>>(ei, deg, ell);
    pad_kernel<<<(N + 255) / 256, 256, 0, stream>>>(deg, ell);
    hist_kernel<<<(N + 255) / 256, 256, 0, stream>>>(deg, hist);
    scan_kernel<<<1, 1, 0, stream>>>(hist);
    scatter_perm_kernel<<<(N + 255) / 256, 256, 0, stream>>>(deg, hist, perm);
    xw_kernel<<<(N + 63) / 64, 256, 0, stream>>>(x, W1a, bufA);

    int nb = (N + 63) / 64;

    layer_kernel<true><<<nb, 256, 0, stream>>>(
        bufA, ell, deg, perm, nullptr, nullptr, nullptr, b1a,
        nullptr, nullptr, W1b, b1b, bufB, partials);
    reduce_stats_kernel<<<128, 64, 0, stream>>>(partials, stats, nb);

    layer_kernel<false><<<nb, 256, 0, stream>>>(
        bufB, ell, deg, perm, stats, gammas, betas, nullptr,
        Wa, ba, Wb, bb, bufA, partials);
    reduce_stats_kernel<<<128, 64, 0, stream>>>(partials, stats + 128, nb);

    layer_kernel<false><<<nb, 256, 0, stream>>>(
        bufA, ell, deg, perm, stats + 128, gammas + 64, betas + 64, nullptr,
        Wa + 4096, ba + 64, Wb + 4096, bb + 64, bufB, partials);
    reduce_stats_kernel<<<128, 64, 0, stream>>>(partials, stats + 256, nb);

    layer_kernel<false><<<nb, 256, 0, stream>>>(
        bufB, ell, deg, perm, stats + 256, gammas + 128, betas + 128, nullptr,
        Wa + 8192, ba + 128, Wb + 8192, bb + 128, bufA, partials);
    reduce_stats_kernel<<<128, 64, 0, stream>>>(partials, stats + 384, nb);

    layer_kernel<false><<<nb, 256, 0, stream>>>(
        bufA, ell, deg, perm, stats + 384, gammas + 192, betas + 192, nullptr,
        Wa + 12288, ba + 192, Wb + 12288, bb + 192, bufB, partials);
    reduce_stats_kernel<<<128, 64, 0, stream>>>(partials, stats + 512, nb);

    pool_head_kernel<<<G, 256, 0, stream>>>(
        bufB, batch, stats + 512, gammas + 256, betas + 256,
        fc1w, fc1b, fc2w, fc2b, out);
}

// Round 6
// 467.638 us; speedup vs baseline: 1.4100x; 1.4100x over previous
//
#include <hip/hip_runtime.h>
#include <hip/hip_fp16.h>

// GIN (5 layers) + BN + pool + MLP head, fused pipeline for MI355X. Round 8.
// R7's degree-sort was right in spirit, fatally contended in implementation:
// hist+scatter did 100K global atomics onto 65 ints (~200us, same same-line
// RMW serialization removed from stats in R6). R8: contention-free counting
// sort: (A) per-block LDS hist -> histLoc[98][65]; (B) one block scans
// bin-major -> per-block per-bin offsets + binBase; (C) per-block LDS-rank
// scatter. No global atomics in the sort path. Everything else = R7.

constexpr int N = 50000;
constexpr int E = 800000;
constexpr int G = 128;
constexpr int MAXDEG = 64;
constexpr int SB = 512;          // nodes per sort block
constexpr float BN_EPS = 1e-5f;

__device__ inline float4 ld4(const float* p) { return *(const float4*)p; }
__device__ inline void st4(float* p, float4 v) { *(float4*)p = v; }

// accumulate 8 halves (raw float4 bits) into float a[8]
__device__ inline void acc8(float* a, float4 raw) {
    const __half2* h2 = (const __half2*)&raw;
#pragma unroll
    for (int i = 0; i < 4; i++) {
        float2 f2 = __half22float2(h2[i]);
        a[2 * i] += f2.x; a[2 * i + 1] += f2.y;
    }
}

union HF2 { __half2 h2[2]; float2 f2; };

__global__ __launch_bounds__(256) void count_fill_kernel(
    const int* __restrict__ ei, int* __restrict__ deg, unsigned short* __restrict__ ell)
{
    int e = blockIdx.x * 256 + threadIdx.x;
    if (e < E) {
        int s = ei[e];
        int d = ei[E + e];
        int slot = atomicAdd(&deg[d], 1);
        if (slot < MAXDEG) ell[d * MAXDEG + slot] = (unsigned short)s;
    }
}

// pad each ELL row to a multiple of 8 slots with the zero-row index N
__global__ __launch_bounds__(256) void pad_kernel(
    const int* __restrict__ deg, unsigned short* __restrict__ ell)
{
    int n = blockIdx.x * 256 + threadIdx.x;
    if (n < N) {
        int dgc = min(deg[n], MAXDEG);
        int p = (dgc + 7) & ~7;
        for (int s = dgc; s < p; s++) ell[n * MAXDEG + s] = (unsigned short)N;
    }
}

// ---- contention-free degree counting sort ----
// A: per-block LDS histogram
__global__ __launch_bounds__(256) void local_hist_kernel(
    const int* __restrict__ deg, int* __restrict__ histLoc)
{
    __shared__ int h[65];
    int t = threadIdx.x;
    if (t < 65) h[t] = 0;
    __syncthreads();
    int base = blockIdx.x * SB;
    for (int i = t; i < SB; i += 256) {
        int n = base + i;
        if (n < N) atomicAdd(&h[min(deg[n], MAXDEG)], 1);
    }
    __syncthreads();
    if (t < 65) histLoc[blockIdx.x * 65 + t] = h[t];
}

// B: bin-major scan; histLoc becomes within-bin block prefix; binBase = bin start
__global__ __launch_bounds__(128) void sort_scan_kernel(
    int* __restrict__ histLoc, int* __restrict__ binBase, int nsb)
{
    int b = threadIdx.x;
    if (b < 65) {
        int run = 0;
        for (int k = 0; k < nsb; k++) {
            int v = histLoc[k * 65 + b];
            histLoc[k * 65 + b] = run;
            run += v;
        }
        binBase[b] = run;   // total per bin (temporarily)
    }
    __syncthreads();
    if (b == 0) {
        int base = 0;
        for (int i = 0; i <= MAXDEG; i++) { int t2 = binBase[i]; binBase[i] = base; base += t2; }
    }
}

// C: per-block scatter using LDS offsets (LDS atomics only)
__global__ __launch_bounds__(256) void scatter_perm_kernel(
    const int* __restrict__ deg, const int* __restrict__ histLoc,
    const int* __restrict__ binBase, int* __restrict__ perm)
{
    __shared__ int off[65];
    int t = threadIdx.x;
    if (t < 65) off[t] = binBase[t] + histLoc[blockIdx.x * 65 + t];
    __syncthreads();
    int base = blockIdx.x * SB;
    for (int i = t; i < SB; i += 256) {
        int n = base + i;
        if (n < N) {
            int slot = atomicAdd(&off[min(deg[n], MAXDEG)], 1);
            perm[slot] = n;
        }
    }
}

// out[n][64] = x[n][128] @ W[128][64], stored fp16; 64 rows per block
__global__ __launch_bounds__(256) void xw_kernel(
    const float* __restrict__ x, const float* __restrict__ W, __half* __restrict__ out)
{
    int tid = threadIdx.x;
    int ty = tid >> 4, tx = tid & 15;
    int base = blockIdx.x * 64;

    float acc[4][4];
#pragma unroll
    for (int r = 0; r < 4; r++)
#pragma unroll
        for (int cc = 0; cc < 4; cc++) acc[r][cc] = 0.f;

    int rr[4];
#pragma unroll
    for (int r = 0; r < 4; r++) rr[r] = min(base + 4 * ty + r, N - 1);

#pragma unroll 4
    for (int c = 0; c < 128; c++) {
        float4 w4 = ld4(W + c * 64 + 4 * tx);
#pragma unroll
        for (int r = 0; r < 4; r++) {
            float a = x[(size_t)rr[r] * 128 + c];
            acc[r][0] += a * w4.x; acc[r][1] += a * w4.y;
            acc[r][2] += a * w4.z; acc[r][3] += a * w4.w;
        }
    }
#pragma unroll
    for (int r = 0; r < 4; r++) {
        int node = base + 4 * ty + r;
        if (node < N) {
            HF2 u;
            u.h2[0] = __floats2half2_rn(acc[r][0], acc[r][1]);
            u.h2[1] = __floats2half2_rn(acc[r][2], acc[r][3]);
            *(float2*)(out + (size_t)node * 64 + 4 * tx) = u.f2;
        }
    }
}

// sum nb per-block partials (each 128 floats) into stats[128].
__global__ __launch_bounds__(64) void reduce_stats_kernel(
    const float* __restrict__ partials, float* __restrict__ stats, int nb)
{
    int c = blockIdx.x;
    int lane = threadIdx.x;
    float s = 0.f;
    for (int i = lane; i < nb; i += 64)
        s += partials[(size_t)i * 128 + c];
#pragma unroll
    for (int off = 32; off > 0; off >>= 1)
        s += __shfl_down(s, off, 64);
    if (lane == 0) stats[c] = s;
}

// Fused GIN layer. hin fp16, N+1 rows (row N = zeros). 64 slots per block,
// slot -> node via degree-sorted perm. ELL ushort, rows padded to 8.
template <bool FIRST>
__global__ __launch_bounds__(256) void layer_kernel(
    const __half* __restrict__ hin, const unsigned short* __restrict__ ell,
    const int* __restrict__ deg, const int* __restrict__ perm,
    const float* __restrict__ statsPrev, const float* __restrict__ gamma, const float* __restrict__ beta,
    const float* __restrict__ bias0,
    const float* __restrict__ W1, const float* __restrict__ b1,
    const float* __restrict__ W2, const float* __restrict__ b2,
    __half* __restrict__ hout, float* __restrict__ statsPart)
{
    __shared__ float sV[64 * 68];   // stride 68
    __shared__ float sStat[128];

    int tid = threadIdx.x, lane = tid & 63, wv = tid >> 6;
    if (tid < 128) sStat[tid] = 0.f;

    int base = blockIdx.x * 64;
    int n8 = lane >> 3, f = lane & 7;   // node-sub (8), feature-oct (8)

    // per-lane channel oct f*8..f*8+7 epilogue params
    float sc[8], sh[8], b0[8];
    if constexpr (FIRST) {
#pragma unroll
        for (int q = 0; q < 2; q++) {
            float4 b4 = ld4(bias0 + 8 * f + 4 * q);
            b0[4 * q + 0] = b4.x; b0[4 * q + 1] = b4.y;
            b0[4 * q + 2] = b4.z; b0[4 * q + 3] = b4.w;
        }
    } else {
#pragma unroll
        for (int q = 0; q < 2; q++) {
            float4 s1 = ld4(statsPrev + 8 * f + 4 * q);
            float4 s2 = ld4(statsPrev + 64 + 8 * f + 4 * q);
            float4 g4 = ld4(gamma + 8 * f + 4 * q);
            float4 be4 = ld4(beta + 8 * f + 4 * q);
            float m[4] = { s1.x / N, s1.y / N, s1.z / N, s1.w / N };
            float v2[4] = { s2.x / N, s2.y / N, s2.z / N, s2.w / N };
            float gg[4] = { g4.x, g4.y, g4.z, g4.w };
            float bb4[4] = { be4.x, be4.y, be4.z, be4.w };
#pragma unroll
            for (int i = 0; i < 4; i++) {
                float s = gg[i] * rsqrtf(v2[i] - m[i] * m[i] + BN_EPS);
                sc[4 * q + i] = s;
                sh[4 * q + i] = bb4[i] - m[i] * s;
            }
        }
    }

    // ---- phase A: gather; wave handles 8 slots at a time, 2 rounds ----
#pragma unroll
    for (int kk = 0; kk < 2; kk++) {
        int slot = base + wv * 16 + kk * 8 + n8;
        int nd = (slot < N) ? perm[slot] : N;
        int dg = (slot < N) ? deg[nd] : 0;
        int dgc = min(dg, MAXDEG);
        int p = (dgc + 7) & ~7;
        const unsigned short* row = ell + (size_t)nd * MAXDEG;

        float a0[8], a1[8], a2[8], a3[8];
#pragma unroll
        for (int i = 0; i < 8; i++) { a0[i] = 0.f; a1[i] = 0.f; a2[i] = 0.f; a3[i] = 0.f; }

        float4 rown = ld4((const float*)(hin + (size_t)nd * 64 + 8 * f));
        for (int j = 0; j < p; j += 8) {
            uint4 iv = *(const uint4*)(row + j);
            int i0 = iv.x & 0xFFFF, i1 = (int)(iv.x >> 16);
            int i2 = iv.y & 0xFFFF, i3 = (int)(iv.y >> 16);
            int i4 = iv.z & 0xFFFF, i5 = (int)(iv.z >> 16);
            int i6 = iv.w & 0xFFFF, i7 = (int)(iv.w >> 16);
            float4 r0 = ld4((const float*)(hin + (size_t)i0 * 64 + 8 * f));
            float4 r1 = ld4((const float*)(hin + (size_t)i1 * 64 + 8 * f));
            float4 r2 = ld4((const float*)(hin + (size_t)i2 * 64 + 8 * f));
            float4 r3 = ld4((const float*)(hin + (size_t)i3 * 64 + 8 * f));
            float4 r4 = ld4((const float*)(hin + (size_t)i4 * 64 + 8 * f));
            float4 r5 = ld4((const float*)(hin + (size_t)i5 * 64 + 8 * f));
            float4 r6 = ld4((const float*)(hin + (size_t)i6 * 64 + 8 * f));
            float4 r7 = ld4((const float*)(hin + (size_t)i7 * 64 + 8 * f));
            acc8(a0, r0); acc8(a1, r1); acc8(a2, r2); acc8(a3, r3);
            acc8(a0, r4); acc8(a1, r5); acc8(a2, r6); acc8(a3, r7);
        }
        acc8(a0, rown);

        float v[8];
#pragma unroll
        for (int i = 0; i < 8; i++) {
            float s = (a0[i] + a1[i]) + (a2[i] + a3[i]);
            if constexpr (FIRST) {
                v[i] = fmaxf(s + b0[i], 0.f);
            } else {
                v[i] = sc[i] * s + (float)(1 + dg) * sh[i];
            }
        }
        int ridx = wv * 16 + kk * 8 + n8;
        st4(sV + ridx * 68 + 8 * f,     make_float4(v[0], v[1], v[2], v[3]));
        st4(sV + ridx * 68 + 8 * f + 4, make_float4(v[4], v[5], v[6], v[7]));
    }
    __syncthreads();

    int ty = tid >> 4, tx = tid & 15;

    if constexpr (!FIRST) {
        // ---- phase B: H = relu(V @ W1 + b1), in-place into sV ----
        float acc[4][4];
#pragma unroll
        for (int cc = 0; cc < 4; cc++) {
            float b = b1[4 * tx + cc];
            acc[0][cc] = b; acc[1][cc] = b; acc[2][cc] = b; acc[3][cc] = b;
        }
#pragma unroll 4
        for (int c = 0; c < 64; c++) {
            float4 w4 = ld4(W1 + c * 64 + 4 * tx);
#pragma unroll
            for (int r = 0; r < 4; r++) {
                float a = sV[(4 * ty + r) * 68 + c];
                acc[r][0] += a * w4.x; acc[r][1] += a * w4.y;
                acc[r][2] += a * w4.z; acc[r][3] += a * w4.w;
            }
        }
        __syncthreads();
#pragma unroll
        for (int r = 0; r < 4; r++)
            st4(sV + (4 * ty + r) * 68 + 4 * tx,
                make_float4(fmaxf(acc[r][0], 0.f), fmaxf(acc[r][1], 0.f),
                            fmaxf(acc[r][2], 0.f), fmaxf(acc[r][3], 0.f)));
        __syncthreads();
    }

    // ---- phase C: O = relu(V @ W2 + b2), store fp16 (perm-scattered), stats ----
    float acc[4][4];
#pragma unroll
    for (int cc = 0; cc < 4; cc++) {
        float b = b2[4 * tx + cc];
        acc[0][cc] = b; acc[1][cc] = b; acc[2][cc] = b; acc[3][cc] = b;
    }
#pragma unroll 4
    for (int c = 0; c < 64; c++) {
        float4 w4 = ld4(W2 + c * 64 + 4 * tx);
#pragma unroll
        for (int r = 0; r < 4; r++) {
            float a = sV[(4 * ty + r) * 68 + c];
            acc[r][0] += a * w4.x; acc[r][1] += a * w4.y;
            acc[r][2] += a * w4.z; acc[r][3] += a * w4.w;
        }
    }
#pragma unroll
    for (int r = 0; r < 4; r++) {
        int slot = base + 4 * ty + r;
        if (slot < N) {
            int node = perm[slot];
            acc[r][0] = fmaxf(acc[r][0], 0.f); acc[r][1] = fmaxf(acc[r][1], 0.f);
            acc[r][2] = fmaxf(acc[r][2], 0.f); acc[r][3] = fmaxf(acc[r][3], 0.f);
            HF2 u;
            u.h2[0] = __floats2half2_rn(acc[r][0], acc[r][1]);
            u.h2[1] = __floats2half2_rn(acc[r][2], acc[r][3]);
            *(float2*)(hout + (size_t)node * 64 + 4 * tx) = u.f2;
        } else {
            acc[r][0] = acc[r][1] = acc[r][2] = acc[r][3] = 0.f;
        }
    }
#pragma unroll
    for (int cc = 0; cc < 4; cc++) {
        float s = 0.f, q = 0.f;
#pragma unroll
        for (int r = 0; r < 4; r++) { s += acc[r][cc]; q += acc[r][cc] * acc[r][cc]; }
        atomicAdd(&sStat[4 * tx + cc], s);
        atomicAdd(&sStat[64 + 4 * tx + cc], q);
    }
    __syncthreads();
    if (tid < 128) statsPart[(size_t)blockIdx.x * 128 + tid] = sStat[tid];
}

// pooled[g] = scale*sum_{n in g} h[n] + cnt*shift; z=relu(p@fc1+b1); z@fc2+b2; log_softmax
__global__ __launch_bounds__(256) void pool_head_kernel(
    const __half* __restrict__ h, const int* __restrict__ batch,
    const float* __restrict__ stats, const float* __restrict__ gamma, const float* __restrict__ beta,
    const float* __restrict__ fc1w, const float* __restrict__ fc1b,
    const float* __restrict__ fc2w, const float* __restrict__ fc2b,
    float* __restrict__ out)
{
    __shared__ float sacc[4][64];
    __shared__ float sp[64];
    __shared__ float sz[64];
    __shared__ float so[10];

    int g = blockIdx.x;
    int lane = threadIdx.x & 63, wv = threadIdx.x >> 6;

    int start, end;
    {
        int lo = 0, hi = N;
        while (lo < hi) { int mid = (lo + hi) >> 1; if (batch[mid] < g) lo = mid + 1; else hi = mid; }
        start = lo;
        lo = start; hi = N;
        while (lo < hi) { int mid = (lo + hi) >> 1; if (batch[mid] < g + 1) lo = mid + 1; else hi = mid; }
        end = lo;
    }

    float acc = 0.f;
    for (int node = start + wv; node < end; node += 4)
        acc += __half2float(h[(size_t)node * 64 + lane]);
    sacc[wv][lane] = acc;
    __syncthreads();

    if (wv == 0) {
        float mean = stats[lane] * (1.f / N);
        float var  = stats[64 + lane] * (1.f / N) - mean * mean;
        float sc = gamma[lane] * rsqrtf(var + BN_EPS);
        float sh = beta[lane] - mean * sc;
        float t = sacc[0][lane] + sacc[1][lane] + sacc[2][lane] + sacc[3][lane];
        sp[lane] = sc * t + (float)(end - start) * sh;
    }
    __syncthreads();
    if (wv == 0) {
        float a = fc1b[lane];
#pragma unroll
        for (int c = 0; c < 64; c++) a += sp[c] * fc1w[c * 64 + lane];
        sz[lane] = fmaxf(a, 0.f);
    }
    __syncthreads();
    if (wv == 0 && lane < 10) {
        float z = fc2b[lane];
#pragma unroll
        for (int j = 0; j < 64; j++) z += sz[j] * fc2w[j * 10 + lane];
        so[lane] = z;
    }
    __syncthreads();
    if (wv == 0 && lane < 10) {
        float m = -1e30f;
#pragma unroll
        for (int c = 0; c < 10; c++) m = fmaxf(m, so[c]);
        float s = 0.f;
#pragma unroll
        for (int c = 0; c < 10; c++) s += expf(so[c] - m);
        out[g * 10 + lane] = so[lane] - m - logf(s);
    }
}

extern "C" void kernel_launch(void* const* d_in, const int* in_sizes, int n_in,
                              void* d_out, int out_size, void* d_ws, size_t ws_size,
                              hipStream_t stream)
{
    const float* x    = (const float*)d_in[0];
    const int*   ei   = (const int*)  d_in[1];
    const int*   batch= (const int*)  d_in[2];
    const float* W1a  = (const float*)d_in[3];
    const float* b1a  = (const float*)d_in[4];
    const float* W1b  = (const float*)d_in[5];
    const float* b1b  = (const float*)d_in[6];
    const float* Wa   = (const float*)d_in[7];
    const float* ba   = (const float*)d_in[8];
    const float* Wb   = (const float*)d_in[9];
    const float* bb   = (const float*)d_in[10];
    const float* gammas = (const float*)d_in[11];
    const float* betas  = (const float*)d_in[12];
    const float* fc1w = (const float*)d_in[13];
    const float* fc1b = (const float*)d_in[14];
    const float* fc2w = (const float*)d_in[15];
    const float* fc2b = (const float*)d_in[16];
    float* out = (float*)d_out;

    int nsb = (N + SB - 1) / SB;   // 98 sort blocks

    // workspace carve (bufA/bufB 128B-aligned so each 64-half row = 1 line)
    char* w = (char*)d_ws;
    int*            deg      = (int*)w;                      // @0          200,000 B (zeroed)
    int*            binBase  = (int*)(w + 200000);           // @200,000    260 B
    float*          stats    = (float*)(w + 200704);         // @200,704    2,560 B
    unsigned short* ell      = (unsigned short*)(w + 203264);// @203,264    6,400,000 B
    int*            perm     = (int*)(w + 6603264);          // @6,603,264  200,000 B
    int*            histLoc  = (int*)(w + 6803328);          // @6,803,328  25,480 B
    __half*         bufA     = (__half*)(w + 6828928);       // @6,828,928  6,400,128 B
    __half*         bufB     = (__half*)(w + 13229056);      // @13,229,056 6,400,128 B
    float*          partials = (float*)(w + 19629184);       // @19,629,184 400,384 B

    hipMemsetAsync(d_ws, 0, 200000, stream);                 // deg only
    hipMemsetAsync(bufA + (size_t)N * 64, 0, 128, stream);   // zero row N
    hipMemsetAsync(bufB + (size_t)N * 64, 0, 128, stream);

    count_fill_kernel<<<(E + 255) / 256, 256, 0, stream>>>(ei, deg, ell);
    pad_kernel<<<(N + 255) / 256, 256, 0, stream>>>(deg, ell);
    local_hist_kernel<<<nsb, 256, 0, stream>>>(deg, histLoc);
    sort_scan_kernel<<<1, 128, 0, stream>>>(histLoc, binBase, nsb);
    scatter_perm_kernel<<<nsb, 256, 0, stream>>>(deg, histLoc, binBase, perm);
    xw_kernel<<<(N + 63) / 64, 256, 0, stream>>>(x, W1a, bufA);

    int nb = (N + 63) / 64;

    layer_kernel<true><<<nb, 256, 0, stream>>>(
        bufA, ell, deg, perm, nullptr, nullptr, nullptr, b1a,
        nullptr, nullptr, W1b, b1b, bufB, partials);
    reduce_stats_kernel<<<128, 64, 0, stream>>>(partials, stats, nb);

    layer_kernel<false><<<nb, 256, 0, stream>>>(
        bufB, ell, deg, perm, stats, gammas, betas, nullptr,
        Wa, ba, Wb, bb, bufA, partials);
    reduce_stats_kernel<<<128, 64, 0, stream>>>(partials, stats + 128, nb);

    layer_kernel<false><<<nb, 256, 0, stream>>>(
        bufA, ell, deg, perm, stats + 128, gammas + 64, betas + 64, nullptr,
        Wa + 4096, ba + 64, Wb + 4096, bb + 64, bufB, partials);
    reduce_stats_kernel<<<128, 64, 0, stream>>>(partials, stats + 256, nb);

    layer_kernel<false><<<nb, 256, 0, stream>>>(
        bufB, ell, deg, perm, stats + 256, gammas + 128, betas + 128, nullptr,
        Wa + 8192, ba + 128, Wb + 8192, bb + 128, bufA, partials);
    reduce_stats_kernel<<<128, 64, 0, stream>>>(partials, stats + 384, nb);

    layer_kernel<false><<<nb, 256, 0, stream>>>(
        bufA, ell, deg, perm, stats + 384, gammas + 192, betas + 192, nullptr,
        Wa + 12288, ba + 192, Wb + 12288, bb + 192, bufB, partials);
    reduce_stats_kernel<<<128, 64, 0, stream>>>(partials, stats + 512, nb);

    pool_head_kernel<<<G, 256, 0, stream>>>(
        bufB, batch, stats + 512, gammas + 256, betas + 256,
        fc1w, fc1b, fc2w, fc2b, out);
}

// Round 7
// 439.566 us; speedup vs baseline: 1.5001x; 1.0639x over previous
//
#include <hip/hip_runtime.h>
#include <hip/hip_fp16.h>

// GIN (5 layers) + BN + pool + MLP head, fused pipeline for MI355X. Round 9.
// R8: contention-free sort worked but cost (~30us incl serial scan) exceeded
// its layer benefit -> dropped. R9 attacks the layer gather chain directly:
//  - packed-fp16 accumulation (__hadd2): 4 pk-adds/row vs 16 cvt+add ->
//    in-loop VALU ~136 -> ~62 inst/iter; 8 partial accumulators (<=8 addends
//    each) bound fp16 rounding; fp32 combine in epilogue.
//  - index prefetch: next uint4 idx load issues before current accumulation.
//  - sort kernels removed (16 launches total).
// Kept from R8: ushort ELL, pad-8, fp16 rows (1 line/row), atomic-free stats.

constexpr int N = 50000;
constexpr int E = 800000;
constexpr int G = 128;
constexpr int MAXDEG = 64;
constexpr float BN_EPS = 1e-5f;

__device__ inline float4 ld4(const float* p) { return *(const float4*)p; }
__device__ inline void st4(float* p, float4 v) { *(float4*)p = v; }

union HF2 { __half2 h2[2]; float2 f2; };

__global__ __launch_bounds__(256) void count_fill_kernel(
    const int* __restrict__ ei, int* __restrict__ deg, unsigned short* __restrict__ ell)
{
    int e = blockIdx.x * 256 + threadIdx.x;
    if (e < E) {
        int s = ei[e];
        int d = ei[E + e];
        int slot = atomicAdd(&deg[d], 1);
        if (slot < MAXDEG) ell[d * MAXDEG + slot] = (unsigned short)s;
    }
}

// pad each ELL row to a multiple of 8 slots with the zero-row index N
__global__ __launch_bounds__(256) void pad_kernel(
    const int* __restrict__ deg, unsigned short* __restrict__ ell)
{
    int n = blockIdx.x * 256 + threadIdx.x;
    if (n < N) {
        int dgc = min(deg[n], MAXDEG);
        int p = (dgc + 7) & ~7;
        for (int s = dgc; s < p; s++) ell[n * MAXDEG + s] = (unsigned short)N;
    }
}

// out[n][64] = x[n][128] @ W[128][64], stored fp16; 64 rows per block
__global__ __launch_bounds__(256) void xw_kernel(
    const float* __restrict__ x, const float* __restrict__ W, __half* __restrict__ out)
{
    int tid = threadIdx.x;
    int ty = tid >> 4, tx = tid & 15;
    int base = blockIdx.x * 64;

    float acc[4][4];
#pragma unroll
    for (int r = 0; r < 4; r++)
#pragma unroll
        for (int cc = 0; cc < 4; cc++) acc[r][cc] = 0.f;

    int rr[4];
#pragma unroll
    for (int r = 0; r < 4; r++) rr[r] = min(base + 4 * ty + r, N - 1);

#pragma unroll 4
    for (int c = 0; c < 128; c++) {
        float4 w4 = ld4(W + c * 64 + 4 * tx);
#pragma unroll
        for (int r = 0; r < 4; r++) {
            float a = x[(size_t)rr[r] * 128 + c];
            acc[r][0] += a * w4.x; acc[r][1] += a * w4.y;
            acc[r][2] += a * w4.z; acc[r][3] += a * w4.w;
        }
    }
#pragma unroll
    for (int r = 0; r < 4; r++) {
        int node = base + 4 * ty + r;
        if (node < N) {
            HF2 u;
            u.h2[0] = __floats2half2_rn(acc[r][0], acc[r][1]);
            u.h2[1] = __floats2half2_rn(acc[r][2], acc[r][3]);
            *(float2*)(out + (size_t)node * 64 + 4 * tx) = u.f2;
        }
    }
}

// sum nb per-block partials (each 128 floats) into stats[128].
__global__ __launch_bounds__(64) void reduce_stats_kernel(
    const float* __restrict__ partials, float* __restrict__ stats, int nb)
{
    int c = blockIdx.x;
    int lane = threadIdx.x;
    float s = 0.f;
    for (int i = lane; i < nb; i += 64)
        s += partials[(size_t)i * 128 + c];
#pragma unroll
    for (int off = 32; off > 0; off >>= 1)
        s += __shfl_down(s, off, 64);
    if (lane == 0) stats[c] = s;
}

// Fused GIN layer. hin fp16, N+1 rows (row N = zeros). 64 nodes per block.
// Gather: packed-fp16 partial accumulation + idx prefetch.
template <bool FIRST>
__global__ __launch_bounds__(256) void layer_kernel(
    const __half* __restrict__ hin, const unsigned short* __restrict__ ell,
    const int* __restrict__ deg,
    const float* __restrict__ statsPrev, const float* __restrict__ gamma, const float* __restrict__ beta,
    const float* __restrict__ bias0,
    const float* __restrict__ W1, const float* __restrict__ b1,
    const float* __restrict__ W2, const float* __restrict__ b2,
    __half* __restrict__ hout, float* __restrict__ statsPart)
{
    __shared__ float sV[64 * 68];   // stride 68
    __shared__ float sStat[128];

    int tid = threadIdx.x, lane = tid & 63, wv = tid >> 6;
    if (tid < 128) sStat[tid] = 0.f;

    int base = blockIdx.x * 64;
    int n8 = lane >> 3, f = lane & 7;   // node-sub (8), feature-oct (8)

    // per-lane channel oct f*8..f*8+7 epilogue params
    float sc[8], sh[8], b0[8];
    if constexpr (FIRST) {
#pragma unroll
        for (int q = 0; q < 2; q++) {
            float4 b4 = ld4(bias0 + 8 * f + 4 * q);
            b0[4 * q + 0] = b4.x; b0[4 * q + 1] = b4.y;
            b0[4 * q + 2] = b4.z; b0[4 * q + 3] = b4.w;
        }
    } else {
#pragma unroll
        for (int q = 0; q < 2; q++) {
            float4 s1 = ld4(statsPrev + 8 * f + 4 * q);
            float4 s2 = ld4(statsPrev + 64 + 8 * f + 4 * q);
            float4 g4 = ld4(gamma + 8 * f + 4 * q);
            float4 be4 = ld4(beta + 8 * f + 4 * q);
            float m[4] = { s1.x / N, s1.y / N, s1.z / N, s1.w / N };
            float v2[4] = { s2.x / N, s2.y / N, s2.z / N, s2.w / N };
            float gg[4] = { g4.x, g4.y, g4.z, g4.w };
            float bb4[4] = { be4.x, be4.y, be4.z, be4.w };
#pragma unroll
            for (int i = 0; i < 4; i++) {
                float s = gg[i] * rsqrtf(v2[i] - m[i] * m[i] + BN_EPS);
                sc[4 * q + i] = s;
                sh[4 * q + i] = bb4[i] - m[i] * s;
            }
        }
    }

    // ---- phase A: gather; wave handles 8 nodes at a time, 2 rounds ----
#pragma unroll
    for (int kk = 0; kk < 2; kk++) {
        int node = base + wv * 16 + kk * 8 + n8;
        int nd = (node < N) ? node : N;
        int dg = (node < N) ? deg[node] : 0;
        int dgc = min(dg, MAXDEG);
        int p = (dgc + 7) & ~7;
        const unsigned short* row = ell + (size_t)nd * MAXDEG;

        // 8 packed-fp16 partial accumulators (one per unrolled row slot);
        // each accumulates <= 8 addends -> bounded rounding.
        __half2 ap[8][4];
#pragma unroll
        for (int r = 0; r < 8; r++)
#pragma unroll
            for (int k = 0; k < 4; k++) ap[r][k] = __half2(__float2half(0.f), __float2half(0.f));

        float4 rown = ld4((const float*)(hin + (size_t)nd * 64 + 8 * f));

        if (p > 0) {
            uint4 iv = *(const uint4*)(row);
            for (int j = 0; j < p; j += 8) {
                uint4 ivn = iv;
                if (j + 8 < p) ivn = *(const uint4*)(row + j + 8);   // prefetch next idx
                int i0 = iv.x & 0xFFFF, i1 = (int)(iv.x >> 16);
                int i2 = iv.y & 0xFFFF, i3 = (int)(iv.y >> 16);
                int i4 = iv.z & 0xFFFF, i5 = (int)(iv.z >> 16);
                int i6 = iv.w & 0xFFFF, i7 = (int)(iv.w >> 16);
                float4 r0 = ld4((const float*)(hin + (size_t)i0 * 64 + 8 * f));
                float4 r1 = ld4((const float*)(hin + (size_t)i1 * 64 + 8 * f));
                float4 r2 = ld4((const float*)(hin + (size_t)i2 * 64 + 8 * f));
                float4 r3 = ld4((const float*)(hin + (size_t)i3 * 64 + 8 * f));
                float4 r4 = ld4((const float*)(hin + (size_t)i4 * 64 + 8 * f));
                float4 r5 = ld4((const float*)(hin + (size_t)i5 * 64 + 8 * f));
                float4 r6 = ld4((const float*)(hin + (size_t)i6 * 64 + 8 * f));
                float4 r7 = ld4((const float*)(hin + (size_t)i7 * 64 + 8 * f));
                iv = ivn;
                const __half2* h0 = (const __half2*)&r0; const __half2* h1 = (const __half2*)&r1;
                const __half2* h2 = (const __half2*)&r2; const __half2* h3 = (const __half2*)&r3;
                const __half2* h4 = (const __half2*)&r4; const __half2* h5 = (const __half2*)&r5;
                const __half2* h6 = (const __half2*)&r6; const __half2* h7 = (const __half2*)&r7;
#pragma unroll
                for (int k = 0; k < 4; k++) {
                    ap[0][k] = __hadd2(ap[0][k], h0[k]);
                    ap[1][k] = __hadd2(ap[1][k], h1[k]);
                    ap[2][k] = __hadd2(ap[2][k], h2[k]);
                    ap[3][k] = __hadd2(ap[3][k], h3[k]);
                    ap[4][k] = __hadd2(ap[4][k], h4[k]);
                    ap[5][k] = __hadd2(ap[5][k], h5[k]);
                    ap[6][k] = __hadd2(ap[6][k], h6[k]);
                    ap[7][k] = __hadd2(ap[7][k], h7[k]);
                }
            }
        }

        // epilogue: fp32 combine of 8 partials + own row
        const __half2* ho = (const __half2*)&rown;
        float v[8];
#pragma unroll
        for (int k = 0; k < 4; k++) {
            float2 s = __half22float2(ho[k]);
#pragma unroll
            for (int r = 0; r < 8; r++) {
                float2 fr = __half22float2(ap[r][k]);
                s.x += fr.x; s.y += fr.y;
            }
            if constexpr (FIRST) {
                v[2 * k]     = fmaxf(s.x + b0[2 * k], 0.f);
                v[2 * k + 1] = fmaxf(s.y + b0[2 * k + 1], 0.f);
            } else {
                float dsh = (float)(1 + dg);
                v[2 * k]     = sc[2 * k] * s.x + dsh * sh[2 * k];
                v[2 * k + 1] = sc[2 * k + 1] * s.y + dsh * sh[2 * k + 1];
            }
        }
        int ridx = wv * 16 + kk * 8 + n8;
        st4(sV + ridx * 68 + 8 * f,     make_float4(v[0], v[1], v[2], v[3]));
        st4(sV + ridx * 68 + 8 * f + 4, make_float4(v[4], v[5], v[6], v[7]));
    }
    __syncthreads();

    int ty = tid >> 4, tx = tid & 15;

    if constexpr (!FIRST) {
        // ---- phase B: H = relu(V @ W1 + b1), in-place into sV ----
        float acc[4][4];
#pragma unroll
        for (int cc = 0; cc < 4; cc++) {
            float b = b1[4 * tx + cc];
            acc[0][cc] = b; acc[1][cc] = b; acc[2][cc] = b; acc[3][cc] = b;
        }
#pragma unroll 4
        for (int c = 0; c < 64; c++) {
            float4 w4 = ld4(W1 + c * 64 + 4 * tx);
#pragma unroll
            for (int r = 0; r < 4; r++) {
                float a = sV[(4 * ty + r) * 68 + c];
                acc[r][0] += a * w4.x; acc[r][1] += a * w4.y;
                acc[r][2] += a * w4.z; acc[r][3] += a * w4.w;
            }
        }
        __syncthreads();
#pragma unroll
        for (int r = 0; r < 4; r++)
            st4(sV + (4 * ty + r) * 68 + 4 * tx,
                make_float4(fmaxf(acc[r][0], 0.f), fmaxf(acc[r][1], 0.f),
                            fmaxf(acc[r][2], 0.f), fmaxf(acc[r][3], 0.f)));
        __syncthreads();
    }

    // ---- phase C: O = relu(V @ W2 + b2), store fp16, stats fp32 ----
    float acc[4][4];
#pragma unroll
    for (int cc = 0; cc < 4; cc++) {
        float b = b2[4 * tx + cc];
        acc[0][cc] = b; acc[1][cc] = b; acc[2][cc] = b; acc[3][cc] = b;
    }
#pragma unroll 4
    for (int c = 0; c < 64; c++) {
        float4 w4 = ld4(W2 + c * 64 + 4 * tx);
#pragma unroll
        for (int r = 0; r < 4; r++) {
            float a = sV[(4 * ty + r) * 68 + c];
            acc[r][0] += a * w4.x; acc[r][1] += a * w4.y;
            acc[r][2] += a * w4.z; acc[r][3] += a * w4.w;
        }
    }
#pragma unroll
    for (int r = 0; r < 4; r++) {
        int node = base + 4 * ty + r;
        if (node < N) {
            acc[r][0] = fmaxf(acc[r][0], 0.f); acc[r][1] = fmaxf(acc[r][1], 0.f);
            acc[r][2] = fmaxf(acc[r][2], 0.f); acc[r][3] = fmaxf(acc[r][3], 0.f);
            HF2 u;
            u.h2[0] = __floats2half2_rn(acc[r][0], acc[r][1]);
            u.h2[1] = __floats2half2_rn(acc[r][2], acc[r][3]);
            *(float2*)(hout + (size_t)node * 64 + 4 * tx) = u.f2;
        } else {
            acc[r][0] = acc[r][1] = acc[r][2] = acc[r][3] = 0.f;
        }
    }
#pragma unroll
    for (int cc = 0; cc < 4; cc++) {
        float s = 0.f, q = 0.f;
#pragma unroll
        for (int r = 0; r < 4; r++) { s += acc[r][cc]; q += acc[r][cc] * acc[r][cc]; }
        atomicAdd(&sStat[4 * tx + cc], s);
        atomicAdd(&sStat[64 + 4 * tx + cc], q);
    }
    __syncthreads();
    if (tid < 128) statsPart[(size_t)blockIdx.x * 128 + tid] = sStat[tid];
}

// pooled[g] = scale*sum_{n in g} h[n] + cnt*shift; z=relu(p@fc1+b1); z@fc2+b2; log_softmax
__global__ __launch_bounds__(256) void pool_head_kernel(
    const __half* __restrict__ h, const int* __restrict__ batch,
    const float* __restrict__ stats, const float* __restrict__ gamma, const float* __restrict__ beta,
    const float* __restrict__ fc1w, const float* __restrict__ fc1b,
    const float* __restrict__ fc2w, const float* __restrict__ fc2b,
    float* __restrict__ out)
{
    __shared__ float sacc[4][64];
    __shared__ float sp[64];
    __shared__ float sz[64];
    __shared__ float so[10];

    int g = blockIdx.x;
    int lane = threadIdx.x & 63, wv = threadIdx.x >> 6;

    int start, end;
    {
        int lo = 0, hi = N;
        while (lo < hi) { int mid = (lo + hi) >> 1; if (batch[mid] < g) lo = mid + 1; else hi = mid; }
        start = lo;
        lo = start; hi = N;
        while (lo < hi) { int mid = (lo + hi) >> 1; if (batch[mid] < g + 1) lo = mid + 1; else hi = mid; }
        end = lo;
    }

    float acc = 0.f;
    for (int node = start + wv; node < end; node += 4)
        acc += __half2float(h[(size_t)node * 64 + lane]);
    sacc[wv][lane] = acc;
    __syncthreads();

    if (wv == 0) {
        float mean = stats[lane] * (1.f / N);
        float var  = stats[64 + lane] * (1.f / N) - mean * mean;
        float sc = gamma[lane] * rsqrtf(var + BN_EPS);
        float sh = beta[lane] - mean * sc;
        float t = sacc[0][lane] + sacc[1][lane] + sacc[2][lane] + sacc[3][lane];
        sp[lane] = sc * t + (float)(end - start) * sh;
    }
    __syncthreads();
    if (wv == 0) {
        float a = fc1b[lane];
#pragma unroll
        for (int c = 0; c < 64; c++) a += sp[c] * fc1w[c * 64 + lane];
        sz[lane] = fmaxf(a, 0.f);
    }
    __syncthreads();
    if (wv == 0 && lane < 10) {
        float z = fc2b[lane];
#pragma unroll
        for (int j = 0; j < 64; j++) z += sz[j] * fc2w[j * 10 + lane];
        so[lane] = z;
    }
    __syncthreads();
    if (wv == 0 && lane < 10) {
        float m = -1e30f;
#pragma unroll
        for (int c = 0; c < 10; c++) m = fmaxf(m, so[c]);
        float s = 0.f;
#pragma unroll
        for (int c = 0; c < 10; c++) s += expf(so[c] - m);
        out[g * 10 + lane] = so[lane] - m - logf(s);
    }
}

extern "C" void kernel_launch(void* const* d_in, const int* in_sizes, int n_in,
                              void* d_out, int out_size, void* d_ws, size_t ws_size,
                              hipStream_t stream)
{
    const float* x    = (const float*)d_in[0];
    const int*   ei   = (const int*)  d_in[1];
    const int*   batch= (const int*)  d_in[2];
    const float* W1a  = (const float*)d_in[3];
    const float* b1a  = (const float*)d_in[4];
    const float* W1b  = (const float*)d_in[5];
    const float* b1b  = (const float*)d_in[6];
    const float* Wa   = (const float*)d_in[7];
    const float* ba   = (const float*)d_in[8];
    const float* Wb   = (const float*)d_in[9];
    const float* bb   = (const float*)d_in[10];
    const float* gammas = (const float*)d_in[11];
    const float* betas  = (const float*)d_in[12];
    const float* fc1w = (const float*)d_in[13];
    const float* fc1b = (const float*)d_in[14];
    const float* fc2w = (const float*)d_in[15];
    const float* fc2b = (const float*)d_in[16];
    float* out = (float*)d_out;

    // workspace carve (bufA/bufB 128B-aligned so each 64-half row = 1 line)
    char* w = (char*)d_ws;
    int*            deg      = (int*)w;                      // @0          200,000 B (zeroed)
    float*          stats    = (float*)(w + 200704);         // @200,704    2,560 B
    unsigned short* ell      = (unsigned short*)(w + 203264);// @203,264    6,400,000 B
    __half*         bufA     = (__half*)(w + 6603264);       // @6,603,264  6,400,128 B
    __half*         bufB     = (__half*)(w + 13003392);      // @13,003,392 6,400,128 B
    float*          partials = (float*)(w + 19403520);       // @19,403,520 400,384 B

    hipMemsetAsync(d_ws, 0, 200000, stream);                 // deg only
    hipMemsetAsync(bufA + (size_t)N * 64, 0, 128, stream);   // zero row N
    hipMemsetAsync(bufB + (size_t)N * 64, 0, 128, stream);

    count_fill_kernel<<<(E + 255) / 256, 256, 0, stream>>>(ei, deg, ell);
    pad_kernel<<<(N + 255) / 256, 256, 0, stream>>>(deg, ell);
    xw_kernel<<<(N + 63) / 64, 256, 0, stream>>>(x, W1a, bufA);

    int nb = (N + 63) / 64;

    layer_kernel<true><<<nb, 256, 0, stream>>>(
        bufA, ell, deg, nullptr, nullptr, nullptr, b1a,
        nullptr, nullptr, W1b, b1b, bufB, partials);
    reduce_stats_kernel<<<128, 64, 0, stream>>>(partials, stats, nb);

    layer_kernel<false><<<nb, 256, 0, stream>>>(
        bufB, ell, deg, stats, gammas, betas, nullptr,
        Wa, ba, Wb, bb, bufA, partials);
    reduce_stats_kernel<<<128, 64, 0, stream>>>(partials, stats + 128, nb);

    layer_kernel<false><<<nb, 256, 0, stream>>>(
        bufA, ell, deg, stats + 128, gammas + 64, betas + 64, nullptr,
        Wa + 4096, ba + 64, Wb + 4096, bb + 64, bufB, partials);
    reduce_stats_kernel<<<128, 64, 0, stream>>>(partials, stats + 256, nb);

    layer_kernel<false><<<nb, 256, 0, stream>>>(
        bufB, ell, deg, stats + 256, gammas + 128, betas + 128, nullptr,
        Wa + 8192, ba + 128, Wb + 8192, bb + 128, bufA, partials);
    reduce_stats_kernel<<<128, 64, 0, stream>>>(partials, stats + 384, nb);

    layer_kernel<false><<<nb, 256, 0, stream>>>(
        bufA, ell, deg, stats + 384, gammas + 192, betas + 192, nullptr,
        Wa + 12288, ba + 192, Wb + 12288, bb + 192, bufB, partials);
    reduce_stats_kernel<<<128, 64, 0, stream>>>(partials, stats + 512, nb);

    pool_head_kernel<<<G, 256, 0, stream>>>(
        bufB, batch, stats + 512, gammas + 256, betas + 256,
        fc1w, fc1b, fc2w, fc2b, out);
}